// Round 8
// baseline (846.245 us; speedup 1.0000x reference)
//
#include <hip/hip_runtime.h>
#include <hip/hip_bf16.h>
#include <stdint.h>

// Problem constants (from reference): B=16, L=4096, D=512, H=512
#define BB 16
#define LL 4096
#define DD 512
#define HH 512
#define MM (BB * LL)   // 65536 tokens

typedef _Float16 f16x8 __attribute__((ext_vector_type(8)));
typedef float f32x4 __attribute__((ext_vector_type(4)));

// ===========================================================================
// conv_b + len (merged launch): w1 (D,H) -> Bh/Bl f16 tiles (scaled by 64,
// residual scaled 4096), n-major, fragment-packed + swizzled (R5-proven
// pairing with the gemm's qb read offsets); block 128 does the per-row
// length binary search (mask rows are monotone 1..10..0).
// ===========================================================================
__global__ __launch_bounds__(256) void convb_len_kernel(
    const float* __restrict__ W1, _Float16* __restrict__ Bh, _Float16* __restrict__ Bl,
    const float* __restrict__ mask, int* __restrict__ lenb)
{
    if (blockIdx.x == 128) {
        const int b = threadIdx.x;
        if (b < BB) {
            const float* row = mask + b * LL;
            int lo = 0, hi = LL;
            while (lo < hi) {
                const int mid = (lo + hi) >> 1;
                if (row[mid] == 0.0f) hi = mid; else lo = mid + 1;
            }
            lenb[b] = lo;
        }
        return;
    }
    const int t    = blockIdx.x * 256 + threadIdx.x;   // 0 .. 32767
    const int tile = t >> 9;                           // ht*16 + kt
    const int u    = t & 511;
    const int nl   = u >> 2;
    const int q    = u & 3;
    const int ht   = tile >> 4;
    const int kt   = tile & 15;
    const int g    = q ^ (nl & 3) ^ ((nl >> 2) & 3);

    const int n = ht * 128 + nl;
    const int kbase = kt * 32;
    f16x8 h, l;
#pragma unroll
    for (int e = 0; e < 8; ++e) {
        const int k = kbase + ((e < 4) ? (4 * g + e) : (16 + 4 * g + (e - 4)));
        const float v = W1[(size_t)k * HH + n] * 64.0f;
        const _Float16 hh = (_Float16)v;
        const float r = v - (float)hh;
        h[e] = hh;
        l[e] = (_Float16)(r * 4096.0f);
    }
    *reinterpret_cast<f16x8*>(Bh + (size_t)tile * 4096 + u * 8) = h;
    *reinterpret_cast<f16x8*>(Bl + (size_t)tile * 4096 + u * 8) = l;
}

__device__ __forceinline__ void gload16(const void* g, void* l)
{
    __builtin_amdgcn_global_load_lds(
        (const __attribute__((address_space(1))) unsigned int*)g,
        (__attribute__((address_space(3))) unsigned int*)l, 16, 0, 0);
}

// ===========================================================================
// MFMA GEMM (R5 structure, SINGLE-buffered LDS): 4x1 wave grid, wave w owns
// rows w*32..w*32+31, all 128 h-cols. A staged fp32 via global_load_lds
// (16 KB), Bh/Bl staged f16 (8+8 KB) -> 32 KB total -> 4 blocks/CU
// (launch_bounds(256,4) caps VGPR at 128). Inter-block overlap hides the
// per-kt barrier drains that the dropped double-buffer used to hide.
// Arithmetic bit-identical to R5.
// ===========================================================================
__global__ __launch_bounds__(256, 4) void gemm_mfma_kernel(
    const float* __restrict__ A,
    const _Float16* __restrict__ Bh, const _Float16* __restrict__ Bl,
    const float* __restrict__ B1,    const float* __restrict__ W2,
    float* __restrict__ part)        // (4, M): p = ht
{
    __shared__ __align__(16) char lds[32768];   // [A:0..16K | Bh:16K | Bl:24K]

    // XCD decode: d = x + 8*ht + 32*mt_local ; mt = x*64 + mt_local
    const int d  = blockIdx.x;
    const int x  = d & 7;
    const int ht = (d >> 3) & 3;
    const int mt = x * 64 + (d >> 5);

    const int tid  = threadIdx.x;
    const int lane = tid & 63;
    const int w    = tid >> 6;       // wave 0..3 -> rows w*32..w*32+31
    const int c    = lane & 15;
    const int g    = lane >> 4;

    int aoff[2][2], boff[8];
    const int qb = g ^ (c & 3) ^ ((c >> 2) & 3);
#pragma unroll
    for (int mf = 0; mf < 2; ++mf) {
        const int r = w * 32 + mf * 16 + c;
        aoff[mf][0] = r * 128 + ((g ^ (c & 7)) << 4);
        aoff[mf][1] = r * 128 + (((g + 4) ^ (c & 7)) << 4);
    }
#pragma unroll
    for (int nf = 0; nf < 8; ++nf)
        boff[nf] = (nf * 16 + c) * 64 + (qb << 4);

    f32x4 accM[2][8] = {};
    f32x4 accL[2][8] = {};

    auto stage = [&](int kt) {
#pragma unroll
        for (int i = 0; i < 4; ++i) {                   // A: 1024 fp32x4 slots
            const int s   = tid + i * 256;
            const int row = s >> 3;
            const int kc  = (s & 7) ^ (row & 7);
            gload16(A + ((size_t)(mt * 128 + row)) * DD + kt * 32 + kc * 4,
                    lds + s * 16);
        }
        const _Float16* s2 = Bh + ((size_t)(ht * 16 + kt)) * 4096;
        const _Float16* s3 = Bl + ((size_t)(ht * 16 + kt)) * 4096;
#pragma unroll
        for (int i = 0; i < 2; ++i) {                   // B: 512 slots each
            const int s = tid + i * 256;
            gload16(s2 + s * 8, lds + 16384 + s * 16);
            gload16(s3 + s * 8, lds + 24576 + s * 16);
        }
    };

    for (int kt = 0; kt < 16; ++kt) {
        stage(kt);
        __syncthreads();                 // staged data ready (vmcnt drain)

        // A fragments: load fp32, split hi/lo (bit-identical to conv arithmetic)
        f16x8 ah[2], al[2];
#pragma unroll
        for (int mf = 0; mf < 2; ++mf) {
            const f32x4 v0 = *reinterpret_cast<const f32x4*>(lds + aoff[mf][0]);
            const f32x4 v1 = *reinterpret_cast<const f32x4*>(lds + aoff[mf][1]);
            const float v[8] = {v0[0], v0[1], v0[2], v0[3], v1[0], v1[1], v1[2], v1[3]};
            f16x8 h, lo;
#pragma unroll
            for (int e = 0; e < 8; ++e) {
                const _Float16 hh = (_Float16)v[e];
                h[e]  = hh;
                lo[e] = (_Float16)((v[e] - (float)hh) * 4096.0f);
            }
            ah[mf] = h;
            al[mf] = lo;
        }
#pragma unroll
        for (int nf = 0; nf < 8; ++nf) {
            const f16x8 bh = *reinterpret_cast<const f16x8*>(lds + 16384 + boff[nf]);
            const f16x8 bl = *reinterpret_cast<const f16x8*>(lds + 24576 + boff[nf]);
#pragma unroll
            for (int mf = 0; mf < 2; ++mf) {
                accM[mf][nf] = __builtin_amdgcn_mfma_f32_16x16x32_f16(ah[mf], bh, accM[mf][nf], 0, 0, 0);
                accL[mf][nf] = __builtin_amdgcn_mfma_f32_16x16x32_f16(ah[mf], bl, accL[mf][nf], 0, 0, 0);
                accL[mf][nf] = __builtin_amdgcn_mfma_f32_16x16x32_f16(al[mf], bh, accL[mf][nf], 0, 0, 0);
            }
        }
        if (kt + 1 < 16) __syncthreads();   // all reads done before restage
    }

    // ---- epilogue: y = (accM + accL/4096)/64 + b1 ; relu ; dot w2 ---------
    float w2v[8], b1v[8];
#pragma unroll
    for (int nf = 0; nf < 8; ++nf) {
        const int n = ht * 128 + nf * 16 + c;
        w2v[nf] = W2[n];
        b1v[nf] = B1[n];
    }
    float red[2][4];
#pragma unroll
    for (int mf = 0; mf < 2; ++mf)
#pragma unroll
        for (int r = 0; r < 4; ++r) {
            float s = 0.0f;
#pragma unroll
            for (int nf = 0; nf < 8; ++nf) {
                float y = (accM[mf][nf][r] + accL[mf][nf][r] * (1.0f / 4096.0f)) * (1.0f / 64.0f) + b1v[nf];
                y = (y > 0.0f) ? y : 0.0f;
                s = fmaf(y, w2v[nf], s);
            }
            red[mf][r] = s;
        }
#pragma unroll
    for (int step = 1; step < 16; step <<= 1)
#pragma unroll
        for (int mf = 0; mf < 2; ++mf)
#pragma unroll
            for (int r = 0; r < 4; ++r)
                red[mf][r] += __shfl_xor(red[mf][r], step);
    if (c == 0) {
#pragma unroll
        for (int mf = 0; mf < 2; ++mf)
#pragma unroll
            for (int r = 0; r < 4; ++r) {
                const int m = mt * 128 + w * 32 + mf * 16 + g * 4 + r;
                part[(size_t)ht * MM + m] = red[mf][r];
            }
    }
}

// ===========================================================================
// FALLBACK fp32 GEMM (used only if workspace too small) -> 8 partials
// ===========================================================================
#define BM 64
#define BN 64
#define BK 32

__global__ __launch_bounds__(256) void mlp_gemm_kernel(
    const float* __restrict__ A, const float* __restrict__ W1,
    const float* __restrict__ B1, const float* __restrict__ W2,
    float* __restrict__ part)
{
    __shared__ __align__(16) float As[BK][BM];
    __shared__ __align__(16) float Bs[BK][BN];
    __shared__ float red[64][17];

    const int ht = blockIdx.x;
    const int mt = blockIdx.y;
    const int t  = threadIdx.x;
    const int tx = t & 15;
    const int ty = t >> 4;
    const int row0 = mt * BM;
    const int n0   = ht * BN;

    float acc[4][4];
#pragma unroll
    for (int i = 0; i < 4; ++i)
#pragma unroll
        for (int j = 0; j < 4; ++j) acc[i][j] = 0.0f;

    for (int k0 = 0; k0 < DD; k0 += BK) {
#pragma unroll
        for (int i = 0; i < 2; ++i) {
            const int idx = t + i * 256;
            const int m   = idx >> 3;
            const int kq  = idx & 7;
            const float4 a = *reinterpret_cast<const float4*>(
                &A[(size_t)(row0 + m) * DD + k0 + kq * 4]);
            As[kq * 4 + 0][m] = a.x;
            As[kq * 4 + 1][m] = a.y;
            As[kq * 4 + 2][m] = a.z;
            As[kq * 4 + 3][m] = a.w;
        }
#pragma unroll
        for (int i = 0; i < 2; ++i) {
            const int idx = t + i * 256;
            const int kk  = idx >> 4;
            const int nq  = idx & 15;
            const float4 bv = *reinterpret_cast<const float4*>(
                &W1[(size_t)(k0 + kk) * HH + n0 + nq * 4]);
            *reinterpret_cast<float4*>(&Bs[kk][nq * 4]) = bv;
        }
        __syncthreads();
#pragma unroll
        for (int k = 0; k < BK; ++k) {
            const float4 av = *reinterpret_cast<const float4*>(&As[k][ty * 4]);
            const float4 bv = *reinterpret_cast<const float4*>(&Bs[k][tx * 4]);
            const float a[4]  = {av.x, av.y, av.z, av.w};
            const float bb[4] = {bv.x, bv.y, bv.z, bv.w};
#pragma unroll
            for (int i = 0; i < 4; ++i)
#pragma unroll
                for (int j = 0; j < 4; ++j)
                    acc[i][j] = fmaf(a[i], bb[j], acc[i][j]);
        }
        __syncthreads();
    }

    const float4 b1v = *reinterpret_cast<const float4*>(&B1[n0 + tx * 4]);
    const float4 w2v = *reinterpret_cast<const float4*>(&W2[n0 + tx * 4]);
    const float b1a[4] = {b1v.x, b1v.y, b1v.z, b1v.w};
    const float w2a[4] = {w2v.x, w2v.y, w2v.z, w2v.w};
#pragma unroll
    for (int i = 0; i < 4; ++i) {
        float p = 0.0f;
#pragma unroll
        for (int j = 0; j < 4; ++j) {
            float y = acc[i][j] + b1a[j];
            y = (y > 0.0f) ? y : 0.0f;
            p = fmaf(y, w2a[j], p);
        }
        red[ty * 4 + i][tx] = p;
    }
    __syncthreads();
    if (t < 64) {
        float s = 0.0f;
#pragma unroll
        for (int q = 0; q < 16; ++q) s += red[t][q];
        part[(size_t)ht * MM + row0 + t] = s;
    }
}

// ===========================================================================
// Row scan: one block per batch row, 1024 threads x 4 tokens.
// flags + ballot/shfl prefix scan -> compacted bpos, nb, smask. One barrier.
// NP = number of logit partials (4 fast path, 8 fallback) — compile-time.
// ===========================================================================
template <int NP>
__global__ __launch_bounds__(1024) void rowscan_kernel(
    const float* __restrict__ part, const float* __restrict__ u,
    const float* __restrict__ b2,   const int* __restrict__ lenb,
    int* __restrict__ bpos, int* __restrict__ nb, float* __restrict__ smask_out)
{
    __shared__ int wtot[16];
    const int b    = blockIdx.x;
    const int tid  = threadIdx.x;
    const int lane = tid & 63;
    const int wid  = tid >> 6;
    const int base = b * LL;
    const int len  = lenb[b];
    const float b2v = b2[0];

    int h[4];
    int cnt = 0;
#pragma unroll
    for (int j = 0; j < 4; ++j) {
        const int l = tid * 4 + j;
        float logit = b2v;
#pragma unroll
        for (int p = 0; p < NP; ++p) logit += part[(size_t)p * MM + base + l];
        const float uu = u[base + l];
        const float xx = logit + logf(uu) - log1pf(-uu);
        int hh = (xx > 0.0f && l < len) ? 1 : 0;
        if (len < LL && l == len - 1) hh = 1;
        h[j] = hh;
        cnt += hh;
    }

    // wave-level inclusive scan of per-thread counts
    int incl = cnt;
#pragma unroll
    for (int s = 1; s < 64; s <<= 1) {
        const int v = __shfl_up(incl, s);
        if (lane >= s) incl += v;
    }
    if (lane == 63) wtot[wid] = incl;
    __syncthreads();

    int woff = 0, tot = 0;
#pragma unroll
    for (int i = 0; i < 16; ++i) {
        const int wi = wtot[i];
        woff += (i < wid) ? wi : 0;
        tot  += wi;
    }

    int pos = woff + incl - cnt;
#pragma unroll
    for (int j = 0; j < 4; ++j) {
        if (h[j]) {
            bpos[base + pos] = tid * 4 + j;
            ++pos;
        }
    }
#pragma unroll
    for (int j = 0; j < 4; ++j) {
        const int l = tid * 4 + j;
        smask_out[base + l] = (l < tot) ? 1.0f : 0.0f;
    }
    if (tid == 0) nb[b] = tot;
}

// ===========================================================================
// Segment mean pooling (R4-proven geometry: one block per (b,s), 128 thr)
// ===========================================================================
__global__ __launch_bounds__(128) void pool_kernel(
    const float* __restrict__ hidden, const int* __restrict__ bpos,
    const int* __restrict__ nb, float* __restrict__ out)
{
    const int blk = blockIdx.x;
    const int b   = blk >> 12;
    const int s   = blk & (LL - 1);
    const int tid = threadIdx.x;
    const int base = b * LL;

    float ax = 0.0f, ay = 0.0f, az = 0.0f, aw = 0.0f;
    const int n = nb[b];
    if (s < n) {
        const int start = (s == 0) ? 0 : (bpos[base + s - 1] + 1);
        const int end   = bpos[base + s];
        const float inv = 1.0f / (float)(end - start + 1);
        for (int tkn = start; tkn <= end; ++tkn) {
            const float4 v = *reinterpret_cast<const float4*>(
                &hidden[((size_t)(base + tkn)) * DD + tid * 4]);
            ax += v.x; ay += v.y; az += v.z; aw += v.w;
        }
        ax *= inv; ay *= inv; az *= inv; aw *= inv;
    }
    float4 r; r.x = ax; r.y = ay; r.z = az; r.w = aw;
    *reinterpret_cast<float4*>(&out[((size_t)(base + s)) * DD + tid * 4]) = r;
}

// ===========================================================================
// Scalars
// ===========================================================================
__global__ void finalize_kernel(
    const int* __restrict__ nb, const int* __restrict__ lenb,
    float* __restrict__ out)
{
    if (threadIdx.x == 0 && blockIdx.x == 0) {
        int k = 0, n = 0;
        for (int b = 0; b < BB; ++b) { k += nb[b]; n += lenb[b]; }
        const double dk = (double)k, dn = (double)n, p = 0.25;
        const double logc = lgamma(dn + 1.0) - lgamma(dk + 1.0) - lgamma(dn - dk + 1.0);
        const double loss = -(logc + dk * log(p) + (dn - dk) * log1p(-p)) / dn;
        out[0] = (float)loss;
        out[1] = (float)k;
        out[2] = (float)n;
    }
}

// ===========================================================================
extern "C" void kernel_launch(void* const* d_in, const int* in_sizes, int n_in,
                              void* d_out, int out_size, void* d_ws, size_t ws_size,
                              hipStream_t stream) {
    const float* hidden = (const float*)d_in[0];
    const float* mask   = (const float*)d_in[1];
    const float* u      = (const float*)d_in[2];
    const float* w1     = (const float*)d_in[3];
    const float* b1     = (const float*)d_in[4];
    const float* w2     = (const float*)d_in[5];
    const float* b2     = (const float*)d_in[6];
    float* out = (float*)d_out;

    const size_t BH_BYTES   = (size_t)64 * 4096 * 2;     // 512 KB each
    const size_t PART_BYTES = (size_t)8 * MM * 4;        // room for 8 partials
    const size_t BPOS_BYTES = (size_t)MM * 4;            // 256 KB
    const size_t need = BH_BYTES * 2 + PART_BYTES + BPOS_BYTES + 4096;

    const size_t P = (size_t)MM * DD;
    float* smask = out + P + 3;

    char* ws = (char*)d_ws;
    const bool fast = (ws_size >= need);

    char* tail = fast ? (ws + BH_BYTES * 2) : ws;
    float* part = (float*)tail;
    int*   bpos = (int*)(tail + PART_BYTES);
    int*   nbuf = (int*)(tail + PART_BYTES + BPOS_BYTES);
    int*   lenb = nbuf + BB;

    if (fast) {
        _Float16* Bh = (_Float16*)ws;
        _Float16* Bl = (_Float16*)(ws + BH_BYTES);
        convb_len_kernel<<<129, 256, 0, stream>>>(w1, Bh, Bl, mask, lenb);
        gemm_mfma_kernel<<<2048, 256, 0, stream>>>(hidden, Bh, Bl, b1, w2, part);
        rowscan_kernel<4><<<BB, 1024, 0, stream>>>(part, u, b2, lenb, bpos, nbuf, smask);
    } else {
        convb_len_kernel<<<129, 256, 0, stream>>>(w1, (_Float16*)ws, (_Float16*)ws, mask, lenb);
        mlp_gemm_kernel<<<dim3(8, MM / BM), 256, 0, stream>>>(hidden, w1, b1, w2, part);
        rowscan_kernel<8><<<BB, 1024, 0, stream>>>(part, u, b2, lenb, bpos, nbuf, smask);
    }

    pool_kernel<<<MM, 128, 0, stream>>>(hidden, bpos, nbuf, out);
    finalize_kernel<<<1, 64, 0, stream>>>(nbuf, lenb, out + P);
}

// Round 11
// 325.740 us; speedup vs baseline: 2.5979x; 2.5979x over previous
//
#include <hip/hip_runtime.h>
#include <hip/hip_bf16.h>
#include <stdint.h>

// Problem constants (from reference): B=16, L=4096, D=512, H=512
#define BB 16
#define LL 4096
#define DD 512
#define HH 512
#define MM (BB * LL)   // 65536 tokens

typedef _Float16 f16x8 __attribute__((ext_vector_type(8)));
typedef float f32x4 __attribute__((ext_vector_type(4)));

// ===========================================================================
// conv_b + len (merged launch): w1 (D,H) -> Bh/Bl f16 tiles (scaled by 64,
// residual scaled 4096), n-major, fragment-packed + swizzled (R5-proven
// pairing with the gemm's qb read offsets); block 128 does the per-row
// length binary search (mask rows are monotone 1..10..0).
// ===========================================================================
__global__ __launch_bounds__(256) void convb_len_kernel(
    const float* __restrict__ W1, _Float16* __restrict__ Bh, _Float16* __restrict__ Bl,
    const float* __restrict__ mask, int* __restrict__ lenb)
{
    if (blockIdx.x == 128) {
        const int b = threadIdx.x;
        if (b < BB) {
            const float* row = mask + b * LL;
            int lo = 0, hi = LL;
            while (lo < hi) {
                const int mid = (lo + hi) >> 1;
                if (row[mid] == 0.0f) hi = mid; else lo = mid + 1;
            }
            lenb[b] = lo;
        }
        return;
    }
    const int t    = blockIdx.x * 256 + threadIdx.x;   // 0 .. 32767
    const int tile = t >> 9;                           // ht*16 + kt
    const int u    = t & 511;
    const int nl   = u >> 2;
    const int q    = u & 3;
    const int ht   = tile >> 4;
    const int kt   = tile & 15;
    const int g    = q ^ (nl & 3) ^ ((nl >> 2) & 3);

    const int n = ht * 128 + nl;
    const int kbase = kt * 32;
    f16x8 h, l;
#pragma unroll
    for (int e = 0; e < 8; ++e) {
        const int k = kbase + ((e < 4) ? (4 * g + e) : (16 + 4 * g + (e - 4)));
        const float v = W1[(size_t)k * HH + n] * 64.0f;
        const _Float16 hh = (_Float16)v;
        const float r = v - (float)hh;
        h[e] = hh;
        l[e] = (_Float16)(r * 4096.0f);
    }
    *reinterpret_cast<f16x8*>(Bh + (size_t)tile * 4096 + u * 8) = h;
    *reinterpret_cast<f16x8*>(Bl + (size_t)tile * 4096 + u * 8) = l;
}

__device__ __forceinline__ void gload16(const void* g, void* l)
{
    __builtin_amdgcn_global_load_lds(
        (const __attribute__((address_space(1))) unsigned int*)g,
        (__attribute__((address_space(3))) unsigned int*)l, 16, 0, 0);
}

// ===========================================================================
// MFMA GEMM (R5-proven, 113.8 us): DOUBLE-buffered LDS, 4x1 wave grid:
// wave w owns rows w*32..w*32+31 (2 m-fragments), ALL 128 n-cols (8
// n-fragments). A staged fp32 via global_load_lds (16 KB/buf, chunk-swizzle
// kc^(row&7) on the global source, linear LDS dest); Bh/Bl staged f16
// (8+8 KB/buf). In-register hi/lo split, each A element split once.
// 4 partials per token (p = ht). VGPR 116 @ launch_bounds(256,2).
// ===========================================================================
__global__ __launch_bounds__(256, 2) void gemm_mfma_kernel(
    const float* __restrict__ A,
    const _Float16* __restrict__ Bh, const _Float16* __restrict__ Bl,
    const float* __restrict__ B1,    const float* __restrict__ W2,
    float* __restrict__ part)        // (4, M): p = ht
{
    __shared__ __align__(16) char lds[2][32768];   // [buf][A:0..16K | Bh:16K | Bl:24K]

    // XCD decode: d = x + 8*ht + 32*mt_local ; mt = x*64 + mt_local
    const int d  = blockIdx.x;
    const int x  = d & 7;
    const int ht = (d >> 3) & 3;
    const int mt = x * 64 + (d >> 5);

    const int tid  = threadIdx.x;
    const int lane = tid & 63;
    const int w    = tid >> 6;       // wave 0..3 -> rows w*32..w*32+31
    const int c    = lane & 15;
    const int g    = lane >> 4;

    int aoff[2][2], boff[8];
    const int qb = g ^ (c & 3) ^ ((c >> 2) & 3);
#pragma unroll
    for (int mf = 0; mf < 2; ++mf) {
        const int r = w * 32 + mf * 16 + c;
        aoff[mf][0] = r * 128 + ((g ^ (c & 7)) << 4);
        aoff[mf][1] = r * 128 + (((g + 4) ^ (c & 7)) << 4);
    }
#pragma unroll
    for (int nf = 0; nf < 8; ++nf)
        boff[nf] = (nf * 16 + c) * 64 + (qb << 4);

    f32x4 accM[2][8] = {};
    f32x4 accL[2][8] = {};

    auto stage = [&](int kt, int bsel) {
        char* l = &lds[bsel][0];
#pragma unroll
        for (int i = 0; i < 4; ++i) {                   // A: 1024 fp32x4 slots
            const int s   = tid + i * 256;
            const int row = s >> 3;
            const int kc  = (s & 7) ^ (row & 7);
            gload16(A + ((size_t)(mt * 128 + row)) * DD + kt * 32 + kc * 4,
                    l + s * 16);
        }
        const _Float16* s2 = Bh + ((size_t)(ht * 16 + kt)) * 4096;
        const _Float16* s3 = Bl + ((size_t)(ht * 16 + kt)) * 4096;
#pragma unroll
        for (int i = 0; i < 2; ++i) {                   // B: 512 slots each
            const int s = tid + i * 256;
            gload16(s2 + s * 8, l + 16384 + s * 16);
            gload16(s3 + s * 8, l + 24576 + s * 16);
        }
    };

    stage(0, 0);
    int buf = 0;
    for (int kt = 0; kt < 16; ++kt) {
        __syncthreads();                 // staged buf ready; prev reads done
        if (kt + 1 < 16) stage(kt + 1, buf ^ 1);
        const char* base = &lds[buf][0];

        // A fragments: load fp32, split hi/lo (bit-identical to conv arithmetic)
        f16x8 ah[2], al[2];
#pragma unroll
        for (int mf = 0; mf < 2; ++mf) {
            const f32x4 v0 = *reinterpret_cast<const f32x4*>(base + aoff[mf][0]);
            const f32x4 v1 = *reinterpret_cast<const f32x4*>(base + aoff[mf][1]);
            const float v[8] = {v0[0], v0[1], v0[2], v0[3], v1[0], v1[1], v1[2], v1[3]};
            f16x8 h, lo;
#pragma unroll
            for (int e = 0; e < 8; ++e) {
                const _Float16 hh = (_Float16)v[e];
                h[e]  = hh;
                lo[e] = (_Float16)((v[e] - (float)hh) * 4096.0f);
            }
            ah[mf] = h;
            al[mf] = lo;
        }
#pragma unroll
        for (int nf = 0; nf < 8; ++nf) {
            const f16x8 bh = *reinterpret_cast<const f16x8*>(base + 16384 + boff[nf]);
            const f16x8 bl = *reinterpret_cast<const f16x8*>(base + 24576 + boff[nf]);
#pragma unroll
            for (int mf = 0; mf < 2; ++mf) {
                accM[mf][nf] = __builtin_amdgcn_mfma_f32_16x16x32_f16(ah[mf], bh, accM[mf][nf], 0, 0, 0);
                accL[mf][nf] = __builtin_amdgcn_mfma_f32_16x16x32_f16(ah[mf], bl, accL[mf][nf], 0, 0, 0);
                accL[mf][nf] = __builtin_amdgcn_mfma_f32_16x16x32_f16(al[mf], bh, accL[mf][nf], 0, 0, 0);
            }
        }
        buf ^= 1;
    }

    // ---- epilogue: y = (accM + accL/4096)/64 + b1 ; relu ; dot w2 ---------
    float w2v[8], b1v[8];
#pragma unroll
    for (int nf = 0; nf < 8; ++nf) {
        const int n = ht * 128 + nf * 16 + c;
        w2v[nf] = W2[n];
        b1v[nf] = B1[n];
    }
    float red[2][4];
#pragma unroll
    for (int mf = 0; mf < 2; ++mf)
#pragma unroll
        for (int r = 0; r < 4; ++r) {
            float s = 0.0f;
#pragma unroll
            for (int nf = 0; nf < 8; ++nf) {
                float y = (accM[mf][nf][r] + accL[mf][nf][r] * (1.0f / 4096.0f)) * (1.0f / 64.0f) + b1v[nf];
                y = (y > 0.0f) ? y : 0.0f;
                s = fmaf(y, w2v[nf], s);
            }
            red[mf][r] = s;
        }
#pragma unroll
    for (int step = 1; step < 16; step <<= 1)
#pragma unroll
        for (int mf = 0; mf < 2; ++mf)
#pragma unroll
            for (int r = 0; r < 4; ++r)
                red[mf][r] += __shfl_xor(red[mf][r], step);
    if (c == 0) {
#pragma unroll
        for (int mf = 0; mf < 2; ++mf)
#pragma unroll
            for (int r = 0; r < 4; ++r) {
                const int m = mt * 128 + w * 32 + mf * 16 + g * 4 + r;
                part[(size_t)ht * MM + m] = red[mf][r];
            }
    }
}

// ===========================================================================
// FALLBACK fp32 GEMM (used only if workspace too small) -> 8 partials
// ===========================================================================
#define BM 64
#define BN 64
#define BK 32

__global__ __launch_bounds__(256) void mlp_gemm_kernel(
    const float* __restrict__ A, const float* __restrict__ W1,
    const float* __restrict__ B1, const float* __restrict__ W2,
    float* __restrict__ part)
{
    __shared__ __align__(16) float As[BK][BM];
    __shared__ __align__(16) float Bs[BK][BN];
    __shared__ float red[64][17];

    const int ht = blockIdx.x;
    const int mt = blockIdx.y;
    const int t  = threadIdx.x;
    const int tx = t & 15;
    const int ty = t >> 4;
    const int row0 = mt * BM;
    const int n0   = ht * BN;

    float acc[4][4];
#pragma unroll
    for (int i = 0; i < 4; ++i)
#pragma unroll
        for (int j = 0; j < 4; ++j) acc[i][j] = 0.0f;

    for (int k0 = 0; k0 < DD; k0 += BK) {
#pragma unroll
        for (int i = 0; i < 2; ++i) {
            const int idx = t + i * 256;
            const int m   = idx >> 3;
            const int kq  = idx & 7;
            const float4 a = *reinterpret_cast<const float4*>(
                &A[(size_t)(row0 + m) * DD + k0 + kq * 4]);
            As[kq * 4 + 0][m] = a.x;
            As[kq * 4 + 1][m] = a.y;
            As[kq * 4 + 2][m] = a.z;
            As[kq * 4 + 3][m] = a.w;
        }
#pragma unroll
        for (int i = 0; i < 2; ++i) {
            const int idx = t + i * 256;
            const int kk  = idx >> 4;
            const int nq  = idx & 15;
            const float4 bv = *reinterpret_cast<const float4*>(
                &W1[(size_t)(k0 + kk) * HH + n0 + nq * 4]);
            *reinterpret_cast<float4*>(&Bs[kk][nq * 4]) = bv;
        }
        __syncthreads();
#pragma unroll
        for (int k = 0; k < BK; ++k) {
            const float4 av = *reinterpret_cast<const float4*>(&As[k][ty * 4]);
            const float4 bv = *reinterpret_cast<const float4*>(&Bs[k][tx * 4]);
            const float a[4]  = {av.x, av.y, av.z, av.w};
            const float bb[4] = {bv.x, bv.y, bv.z, bv.w};
#pragma unroll
            for (int i = 0; i < 4; ++i)
#pragma unroll
                for (int j = 0; j < 4; ++j)
                    acc[i][j] = fmaf(a[i], bb[j], acc[i][j]);
        }
        __syncthreads();
    }

    const float4 b1v = *reinterpret_cast<const float4*>(&B1[n0 + tx * 4]);
    const float4 w2v = *reinterpret_cast<const float4*>(&W2[n0 + tx * 4]);
    const float b1a[4] = {b1v.x, b1v.y, b1v.z, b1v.w};
    const float w2a[4] = {w2v.x, w2v.y, w2v.z, w2v.w};
#pragma unroll
    for (int i = 0; i < 4; ++i) {
        float p = 0.0f;
#pragma unroll
        for (int j = 0; j < 4; ++j) {
            float y = acc[i][j] + b1a[j];
            y = (y > 0.0f) ? y : 0.0f;
            p = fmaf(y, w2a[j], p);
        }
        red[ty * 4 + i][tx] = p;
    }
    __syncthreads();
    if (t < 64) {
        float s = 0.0f;
#pragma unroll
        for (int q = 0; q < 16; ++q) s += red[t][q];
        part[(size_t)ht * MM + row0 + t] = s;
    }
}

// ===========================================================================
// Row scan: one block per batch row, 1024 threads x 4 tokens.
// flags + ballot/shfl prefix scan -> compacted bpos, nb, smask. One barrier.
// NP = number of logit partials (4 fast path, 8 fallback) — compile-time.
// ===========================================================================
template <int NP>
__global__ __launch_bounds__(1024) void rowscan_kernel(
    const float* __restrict__ part, const float* __restrict__ u,
    const float* __restrict__ b2,   const int* __restrict__ lenb,
    int* __restrict__ bpos, int* __restrict__ nb, float* __restrict__ smask_out)
{
    __shared__ int wtot[16];
    const int b    = blockIdx.x;
    const int tid  = threadIdx.x;
    const int lane = tid & 63;
    const int wid  = tid >> 6;
    const int base = b * LL;
    const int len  = lenb[b];
    const float b2v = b2[0];

    int h[4];
    int cnt = 0;
#pragma unroll
    for (int j = 0; j < 4; ++j) {
        const int l = tid * 4 + j;
        float logit = b2v;
#pragma unroll
        for (int p = 0; p < NP; ++p) logit += part[(size_t)p * MM + base + l];
        const float uu = u[base + l];
        const float xx = logit + logf(uu) - log1pf(-uu);
        int hh = (xx > 0.0f && l < len) ? 1 : 0;
        if (len < LL && l == len - 1) hh = 1;
        h[j] = hh;
        cnt += hh;
    }

    // wave-level inclusive scan of per-thread counts
    int incl = cnt;
#pragma unroll
    for (int s = 1; s < 64; s <<= 1) {
        const int v = __shfl_up(incl, s);
        if (lane >= s) incl += v;
    }
    if (lane == 63) wtot[wid] = incl;
    __syncthreads();

    int woff = 0, tot = 0;
#pragma unroll
    for (int i = 0; i < 16; ++i) {
        const int wi = wtot[i];
        woff += (i < wid) ? wi : 0;
        tot  += wi;
    }

    int pos = woff + incl - cnt;
#pragma unroll
    for (int j = 0; j < 4; ++j) {
        if (h[j]) {
            bpos[base + pos] = tid * 4 + j;
            ++pos;
        }
    }
#pragma unroll
    for (int j = 0; j < 4; ++j) {
        const int l = tid * 4 + j;
        smask_out[base + l] = (l < tot) ? 1.0f : 0.0f;
    }
    if (tid == 0) nb[b] = tot;
}

// ===========================================================================
// Segment mean pooling (R4-proven geometry: one block per (b,s), 128 thr)
// ===========================================================================
__global__ __launch_bounds__(128) void pool_kernel(
    const float* __restrict__ hidden, const int* __restrict__ bpos,
    const int* __restrict__ nb, float* __restrict__ out)
{
    const int blk = blockIdx.x;
    const int b   = blk >> 12;
    const int s   = blk & (LL - 1);
    const int tid = threadIdx.x;
    const int base = b * LL;

    float ax = 0.0f, ay = 0.0f, az = 0.0f, aw = 0.0f;
    const int n = nb[b];
    if (s < n) {
        const int start = (s == 0) ? 0 : (bpos[base + s - 1] + 1);
        const int end   = bpos[base + s];
        const float inv = 1.0f / (float)(end - start + 1);
        for (int tkn = start; tkn <= end; ++tkn) {
            const float4 v = *reinterpret_cast<const float4*>(
                &hidden[((size_t)(base + tkn)) * DD + tid * 4]);
            ax += v.x; ay += v.y; az += v.z; aw += v.w;
        }
        ax *= inv; ay *= inv; az *= inv; aw *= inv;
    }
    float4 r; r.x = ax; r.y = ay; r.z = az; r.w = aw;
    *reinterpret_cast<float4*>(&out[((size_t)(base + s)) * DD + tid * 4]) = r;
}

// ===========================================================================
// Scalars
// ===========================================================================
__global__ void finalize_kernel(
    const int* __restrict__ nb, const int* __restrict__ lenb,
    float* __restrict__ out)
{
    if (threadIdx.x == 0 && blockIdx.x == 0) {
        int k = 0, n = 0;
        for (int b = 0; b < BB; ++b) { k += nb[b]; n += lenb[b]; }
        const double dk = (double)k, dn = (double)n, p = 0.25;
        const double logc = lgamma(dn + 1.0) - lgamma(dk + 1.0) - lgamma(dn - dk + 1.0);
        const double loss = -(logc + dk * log(p) + (dn - dk) * log1p(-p)) / dn;
        out[0] = (float)loss;
        out[1] = (float)k;
        out[2] = (float)n;
    }
}

// ===========================================================================
extern "C" void kernel_launch(void* const* d_in, const int* in_sizes, int n_in,
                              void* d_out, int out_size, void* d_ws, size_t ws_size,
                              hipStream_t stream) {
    const float* hidden = (const float*)d_in[0];
    const float* mask   = (const float*)d_in[1];
    const float* u      = (const float*)d_in[2];
    const float* w1     = (const float*)d_in[3];
    const float* b1     = (const float*)d_in[4];
    const float* w2     = (const float*)d_in[5];
    const float* b2     = (const float*)d_in[6];
    float* out = (float*)d_out;

    const size_t BH_BYTES   = (size_t)64 * 4096 * 2;     // 512 KB each
    const size_t PART_BYTES = (size_t)8 * MM * 4;        // room for 8 partials
    const size_t BPOS_BYTES = (size_t)MM * 4;            // 256 KB
    const size_t need = BH_BYTES * 2 + PART_BYTES + BPOS_BYTES + 4096;

    const size_t P = (size_t)MM * DD;
    float* smask = out + P + 3;

    char* ws = (char*)d_ws;
    const bool fast = (ws_size >= need);

    char* tail = fast ? (ws + BH_BYTES * 2) : ws;
    float* part = (float*)tail;
    int*   bpos = (int*)(tail + PART_BYTES);
    int*   nbuf = (int*)(tail + PART_BYTES + BPOS_BYTES);
    int*   lenb = nbuf + BB;

    if (fast) {
        _Float16* Bh = (_Float16*)ws;
        _Float16* Bl = (_Float16*)(ws + BH_BYTES);
        convb_len_kernel<<<129, 256, 0, stream>>>(w1, Bh, Bl, mask, lenb);
        gemm_mfma_kernel<<<2048, 256, 0, stream>>>(hidden, Bh, Bl, b1, w2, part);
        rowscan_kernel<4><<<BB, 1024, 0, stream>>>(part, u, b2, lenb, bpos, nbuf, smask);
    } else {
        convb_len_kernel<<<129, 256, 0, stream>>>(w1, (_Float16*)ws, (_Float16*)ws, mask, lenb);
        mlp_gemm_kernel<<<dim3(8, MM / BM), 256, 0, stream>>>(hidden, w1, b1, w2, part);
        rowscan_kernel<8><<<BB, 1024, 0, stream>>>(part, u, b2, lenb, bpos, nbuf, smask);
    }

    pool_kernel<<<MM, 128, 0, stream>>>(hidden, bpos, nbuf, out);
    finalize_kernel<<<1, 64, 0, stream>>>(nbuf, lenb, out + P);
}